// Round 7
// baseline (70.325 us; speedup 1.0000x reference)
//
#include <hip/hip_runtime.h>

typedef __attribute__((ext_vector_type(8))) short    short8;   // 8 x bf16 (MFMA A/B frag)
typedef __attribute__((ext_vector_type(4))) float    f32x4;    // MFMA C/D frag
typedef __attribute__((ext_vector_type(4))) unsigned uint4_;
typedef __attribute__((ext_vector_type(2))) unsigned uint2_;

#define HW     16000
#define WWID   200
#define NPARAM 8513
#define REP    4          // diagnostic: repeat compute loop (idempotent re-stores)
// raw param offsets: w0[64][66] @0, w1[64][64] @4224, w2 @8320, b0 @8384, b1 @8448, b2 @8512

__device__ __forceinline__ unsigned f2bf(float f) {   // RNE fp32 -> bf16
    unsigned u = __builtin_bit_cast(unsigned, f);
    return (u + 0x7FFFu + ((u >> 16) & 1u)) >> 16;
}
__device__ __forceinline__ unsigned pkbf2(float a, float b) {
    return f2bf(a) | (f2bf(b) << 16);
}
__device__ __forceinline__ short8 mk8(unsigned a, unsigned b, unsigned c, unsigned d) {
    uint4_ u; u.x = a; u.y = b; u.z = c; u.w = d;
    return __builtin_bit_cast(short8, u);
}

// block = 512 threads (8 waves) = 4 instances x 2 k-halves; tile = 128 px.
// grid (125, N*2): blockIdx.y>>1 = n, &1 = instance group (assumes num_ins==8).
// Per slice s: L0(s+1) -> h0[buf^1] runs CONCURRENTLY with L1/L2(s) from
// h0[buf]; single barrier per slice covers both (write->read never adjacent).
// VGPR budget ~112 -> launch_bounds(512,4): 4 waves/SIMD, 2 blocks/CU.
// LDS: xt 32KB + h0 dbuf 16KB + vpart 512B.
__global__ __launch_bounds__(512, 4) void condlane_pipe(
    const float* __restrict__ x,        // [N, 64, HW]
    const float* __restrict__ params,   // [M, 8513]
    float* __restrict__ out,            // [M, HW]
    int num_ins)
{
    __shared__ char lds_[32768 + 16384 + 512];
    char*  xt     = lds_;
    char*  h0base = lds_ + 32768;                  // 2 bufs * 4 inst * 2048 B
    float* vpart  = (float*)(lds_ + 32768 + 16384);// 2 bufs * 4 inst * 16 px

    const int tid  = threadIdx.x;
    const int lane = tid & 63;
    const int wid  = tid >> 6;          // 0..7
    const int iw   = wid >> 1;          // instance within group 0..3
    const int kh   = wid & 1;           // output-k half
    const int n    = blockIdx.y >> 1;
    const int ig   = blockIdx.y & 1;    // instance group
    const int pxg0 = blockIdx.x * 128;
    const int g    = (lane >> 4) & 3;
    const int px16 = lane & 15;

    // ---- stage x tile: [128 px][128 ch] bf16, swizzle byte ^= (p&15)<<4 ----
    {
        const int p   = tid & 127;
        const int sel = tid >> 7;       // 0..3, 16 fp32 channels each
        const float* xp = x + (size_t)n * 64 * HW + (pxg0 + p);  // 125*128 = HW exactly
        #pragma unroll
        for (int it = 0; it < 2; ++it) {
            int c0 = sel * 16 + it * 8;
            uint4_ d;
            d.x = pkbf2(xp[(size_t)(c0 + 0) * HW], xp[(size_t)(c0 + 1) * HW]);
            d.y = pkbf2(xp[(size_t)(c0 + 2) * HW], xp[(size_t)(c0 + 3) * HW]);
            d.z = pkbf2(xp[(size_t)(c0 + 4) * HW], xp[(size_t)(c0 + 5) * HW]);
            d.w = pkbf2(xp[(size_t)(c0 + 6) * HW], xp[(size_t)(c0 + 7) * HW]);
            *(uint4_*)(xt + ((p * 256 + c0 * 2) ^ ((p & 15) << 4))) = d;
        }
        // const K-channels 64..95 = {lx, ly, 1, 0...}
        const int pg = pxg0 + p;
        float lx = (float)(pg % WWID) * (1.0f / WWID);
        float ly = (float)(pg / WWID) * (1.0f / WWID);   // source bug: also /W
        uint4_ cv;
        cv.x = (sel == 0) ? pkbf2(lx, ly)   : 0u;
        cv.y = (sel == 0) ? pkbf2(1.f, 0.f) : 0u;
        cv.z = 0u; cv.w = 0u;
        *(uint4_*)(xt + ((p * 256 + 128 + sel * 16) ^ ((p & 15) << 4))) = cv;
    }

    // ---- per-wave (half-instance) weight gather into registers ----
    const int mi = ig * 4 + iw;
    const int m  = n * num_ins + mi;
    const float* pm = params + (size_t)m * NPARAM;

    short8 w0f[3][2], w1f[2][2];
    #pragma unroll
    for (int kbl = 0; kbl < 2; ++kbl) {
        const int k = kh * 32 + kbl * 16 + px16;
        #pragma unroll
        for (int ch = 0; ch < 2; ++ch) {
            const float* s0 = pm + k * 66 + 2 + ch * 32 + g * 8;    // w0 x-cols
            w0f[ch][kbl] = mk8(pkbf2(s0[0], s0[1]), pkbf2(s0[2], s0[3]),
                               pkbf2(s0[4], s0[5]), pkbf2(s0[6], s0[7]));
            const float* s1 = pm + 4224 + k * 64 + ch * 32 + g * 8; // w1
            w1f[ch][kbl] = mk8(pkbf2(s1[0], s1[1]), pkbf2(s1[2], s1[3]),
                               pkbf2(s1[4], s1[5]), pkbf2(s1[6], s1[7]));
        }
        // padded K-channels 64..95 = {lx, ly, 1, 0...} -> cols {w00, w01, b0, 0...}
        float a = (g == 0) ? pm[k * 66 + 0] : 0.0f;
        float b = (g == 0) ? pm[k * 66 + 1] : 0.0f;
        float c = (g == 0) ? pm[8384 + k]   : 0.0f;
        w0f[2][kbl] = mk8(pkbf2(a, b), pkbf2(c, 0.0f), 0u, 0u);
    }
    f32x4 bias1[2], w2v[2];
    #pragma unroll
    for (int kbl = 0; kbl < 2; ++kbl)
        #pragma unroll
        for (int j = 0; j < 4; ++j) {
            bias1[kbl][j] = pm[8448 + kh * 32 + kbl * 16 + g * 4 + j];
            w2v[kbl][j]   = pm[8320 + kh * 32 + kbl * 16 + g * 4 + j];
        }
    const float b2 = pm[8512] - 2.19f;

    const int swzx = px16 << 4;
    const int swzh = (px16 & 7) << 4;

    // L0 for slice s -> h0[buf]
    auto do_L0 = [&](int s, int buf) {
        const int pxl = s * 16 + px16;
        short8 xf[3];
        #pragma unroll
        for (int f = 0; f < 3; ++f)
            xf[f] = *(const short8*)(xt + ((pxl * 256 + f * 64 + g * 16) ^ swzx));
        f32x4 acc0[2];
        #pragma unroll
        for (int kbl = 0; kbl < 2; ++kbl)
            #pragma unroll
            for (int j = 0; j < 4; ++j) acc0[kbl][j] = 0.f;
        #pragma unroll
        for (int f = 0; f < 3; ++f)
            #pragma unroll
            for (int kbl = 0; kbl < 2; ++kbl)
                acc0[kbl] = __builtin_amdgcn_mfma_f32_16x16x32_bf16(w0f[f][kbl], xf[f], acc0[kbl], 0, 0, 0);
        char* hb = h0base + buf * 8192 + iw * 2048;
        #pragma unroll
        for (int kbl = 0; kbl < 2; ++kbl) {
            uint2_ pk;
            pk.x = pkbf2(fmaxf(acc0[kbl][0], 0.f), fmaxf(acc0[kbl][1], 0.f));
            pk.y = pkbf2(fmaxf(acc0[kbl][2], 0.f), fmaxf(acc0[kbl][3], 0.f));
            const int cb = kh * 64 + kbl * 32 + g * 8;   // byte col
            *(uint2_*)(hb + ((px16 * 128 + cb) ^ swzh)) = pk;
        }
    };

    #pragma unroll 1
    for (int rep = 0; rep < REP; ++rep) {
        do_L0(0, 0);
        float vprev = 0.f;
        __syncthreads();                 // xt (rep 0) + h0[0] ready
        #pragma unroll
        for (int s = 0; s < 8; ++s) {
            const int buf = s & 1;
            // store slice s-1 (kh=0 combines its reg partial with kh=1's vpart)
            if (s > 0 && kh == 0 && lane < 16)
                out[(size_t)m * HW + pxg0 + (s - 1) * 16 + lane] =
                    vprev + vpart[(buf ^ 1) * 64 + iw * 16 + lane] + b2;
            // next slice's L0 -> h0[buf^1], concurrent with L1/L2(s)
            if (s < 7) do_L0(s + 1, buf ^ 1);
            // L1(s) from h0[buf]
            char* hb = h0base + buf * 8192 + iw * 2048;
            short8 hf[2];
            #pragma unroll
            for (int ch = 0; ch < 2; ++ch)
                hf[ch] = *(const short8*)(hb + ((px16 * 128 + ch * 64 + g * 16) ^ swzh));
            f32x4 acc1[2];
            acc1[0] = bias1[0]; acc1[1] = bias1[1];
            #pragma unroll
            for (int ch = 0; ch < 2; ++ch)
                #pragma unroll
                for (int kbl = 0; kbl < 2; ++kbl)
                    acc1[kbl] = __builtin_amdgcn_mfma_f32_16x16x32_bf16(w1f[ch][kbl], hf[ch], acc1[kbl], 0, 0, 0);
            // L2 partial (this k-half)
            float v = 0.f;
            #pragma unroll
            for (int kbl = 0; kbl < 2; ++kbl)
                #pragma unroll
                for (int j = 0; j < 4; ++j)
                    v += w2v[kbl][j] * fmaxf(acc1[kbl][j], 0.f);
            v += __shfl_xor(v, 16);
            v += __shfl_xor(v, 32);
            if (kh == 1) { if (lane < 16) vpart[buf * 64 + iw * 16 + lane] = v; }
            else vprev = v;
            __syncthreads();             // h0[buf^1] + vpart[buf] complete
        }
        if (kh == 0 && lane < 16)
            out[(size_t)m * HW + pxg0 + 7 * 16 + lane] =
                vprev + vpart[64 + iw * 16 + lane] + b2;
        // next rep's do_L0(0,0) overwrite of h0[0] is safe: last read at s=6,
        // all waves passed the s=7 barrier.
    }
}

extern "C" void kernel_launch(void* const* d_in, const int* in_sizes, int n_in,
                              void* d_out, int out_size, void* d_ws, size_t ws_size,
                              hipStream_t stream) {
    const float* x      = (const float*)d_in[0];
    const float* params = (const float*)d_in[1];
    float* out          = (float*)d_out;

    const int N = in_sizes[0] / (64 * HW);   // 4
    const int M = in_sizes[1] / NPARAM;      // 32
    const int num_ins = M / N;               // 8 (kernel assumes 8: 2 groups x 4)

    dim3 grid((HW + 127) / 128, N * 2);      // 125 x 8 = 1000 blocks
    condlane_pipe<<<grid, 512, 0, stream>>>(x, params, out, num_ins);
}

// Round 8
// 29.040 us; speedup vs baseline: 2.4217x; 2.4217x over previous
//
#include <hip/hip_runtime.h>

typedef __attribute__((ext_vector_type(8)))  short    short8;   // 8 x bf16 (MFMA A/B frag)
typedef __attribute__((ext_vector_type(16))) float    f32x16;   // 32x32 MFMA C/D frag
typedef __attribute__((ext_vector_type(4)))  unsigned uint4_;
typedef __attribute__((ext_vector_type(2)))  unsigned uint2_;

#define HW     16000
#define WWID   200
#define NPARAM 8513
// raw param offsets: w0[64][66] @0, w1[64][64] @4224, w2 @8320, b0 @8384, b1 @8448, b2 @8512

__device__ __forceinline__ unsigned pkbf2(float a, float b) {   // 1 VALU op (RNE)
    unsigned r;
    asm("v_cvt_pk_bf16_f32 %0, %1, %2" : "=v"(r) : "v"(a), "v"(b));
    return r;
}
__device__ __forceinline__ short8 mk8(unsigned a, unsigned b, unsigned c, unsigned d) {
    uint4_ u; u.x = a; u.y = b; u.z = c; u.w = d;
    return __builtin_bit_cast(short8, u);
}

// block = 512 threads (8 waves) = 4 instances x 2 k-halves; tile = 128 px.
// 32x32x16 MFMA: wave computes 32 k-outputs x 32 px per slice (4 slices/tile).
// A-frag: row=lane&31, k=(lane>>5)*8+j. C/D: col=lane&31 (px),
// row=(reg&3)+8*(reg>>2)+4*(lane>>5) (c within k-half).
// Pipeline: do_L0(s+1)->h0[buf^1] concurrent with L1/L2(s) from h0[buf];
// one barrier per slice. LDS: xt 32KB + h0 dbuf 32KB + vpart 1KB = 66560 B
// -> 2 blocks/CU; VGPR capped 128 via launch_bounds -> 4 waves/SIMD.
__global__ __launch_bounds__(512, 4) void condlane_mfma32(
    const float* __restrict__ x,        // [N, 64, HW]
    const float* __restrict__ params,   // [M, 8513]
    float* __restrict__ out,            // [M, HW]
    int num_ins)
{
    extern __shared__ char lds_[];
    char*  xt     = lds_;                       // [128 px][128 ch] bf16, swz (px&15)<<4
    char*  h0base = lds_ + 32768;               // 2 bufs * 4 inst * [32 px][64 c] bf16
    float* vpart  = (float*)(lds_ + 65536);     // 2 bufs * 4 inst * 32 px

    const int tid  = threadIdx.x;
    const int lane = tid & 63;
    const int wid  = tid >> 6;          // 0..7
    const int iw   = wid >> 1;          // instance within group
    const int kh   = wid & 1;           // output-k half
    const int n    = blockIdx.y >> 1;
    const int ig   = blockIdx.y & 1;    // instance group (num_ins==8: 2 groups x 4)
    const int pxg0 = blockIdx.x * 128;
    const int P    = lane & 31;         // px within slice / k-row within half
    const int H    = lane >> 5;

    // ---- stage x tile: [128 px][128 ch] bf16, swizzle byte ^= (p&15)<<4 ----
    {
        const int p   = tid & 127;
        const int sel = tid >> 7;       // 0..3, 16 fp32 channels each
        const float* xp = x + (size_t)n * 64 * HW + (pxg0 + p);  // 125*128 = HW exactly
        #pragma unroll
        for (int it = 0; it < 2; ++it) {
            int c0 = sel * 16 + it * 8;
            uint4_ d;
            d.x = pkbf2(xp[(size_t)(c0 + 0) * HW], xp[(size_t)(c0 + 1) * HW]);
            d.y = pkbf2(xp[(size_t)(c0 + 2) * HW], xp[(size_t)(c0 + 3) * HW]);
            d.z = pkbf2(xp[(size_t)(c0 + 4) * HW], xp[(size_t)(c0 + 5) * HW]);
            d.w = pkbf2(xp[(size_t)(c0 + 6) * HW], xp[(size_t)(c0 + 7) * HW]);
            *(uint4_*)(xt + ((p * 256 + c0 * 2) ^ ((p & 15) << 4))) = d;
        }
        // const K-channels 64..95 = {lx, ly, 1, 0...}
        const int pg = pxg0 + p;
        float lx = (float)(pg % WWID) * (1.0f / WWID);
        float ly = (float)(pg / WWID) * (1.0f / WWID);   // source bug: also /W
        uint4_ cv;
        cv.x = (sel == 0) ? pkbf2(lx, ly) : 0u;
        cv.y = (sel == 0) ? pkbf2(1.f, 0.f) : 0u;
        cv.z = 0u; cv.w = 0u;
        *(uint4_*)(xt + ((p * 256 + 128 + sel * 16) ^ ((p & 15) << 4))) = cv;
    }

    // ---- per-wave (half-instance) weight gather into register fragments ----
    const int m  = n * num_ins + ig * 4 + iw;
    const float* pm = params + (size_t)m * NPARAM;
    const int k = kh * 32 + P;          // this lane's A-row (output k)

    short8 w0f[5], w1f[4];
    #pragma unroll
    for (int ks = 0; ks < 4; ++ks) {
        const float* s0 = pm + k * 66 + 2 + ks * 16 + H * 8;     // w0 x-cols
        w0f[ks] = mk8(pkbf2(s0[0], s0[1]), pkbf2(s0[2], s0[3]),
                      pkbf2(s0[4], s0[5]), pkbf2(s0[6], s0[7]));
        const float* s1 = pm + 4224 + k * 64 + ks * 16 + H * 8;  // w1
        w1f[ks] = mk8(pkbf2(s1[0], s1[1]), pkbf2(s1[2], s1[3]),
                      pkbf2(s1[4], s1[5]), pkbf2(s1[6], s1[7]));
    }
    {   // K-channels 64..79: {lx, ly, 1, 0...} -> cols {w00, w01, b0, 0...}
        float a = (H == 0) ? pm[k * 66 + 0] : 0.f;
        float b = (H == 0) ? pm[k * 66 + 1] : 0.f;
        float c = (H == 0) ? pm[8384 + k]   : 0.f;
        w0f[4] = mk8(pkbf2(a, b), pkbf2(c, 0.f), 0u, 0u);
    }
    f32x16 bias1, w2v;
    #pragma unroll
    for (int q = 0; q < 4; ++q)
        #pragma unroll
        for (int r = 0; r < 4; ++r) {   // acc elem q*4+r <-> c-row kh*32+8q+4H+r
            bias1[q * 4 + r] = pm[8448 + kh * 32 + q * 8 + H * 4 + r];
            w2v[q * 4 + r]   = pm[8320 + kh * 32 + q * 8 + H * 4 + r];
        }
    const float b2 = pm[8512] - 2.19f;

    char* hb_iw = h0base + iw * 4096;
    const int swh = (P & 7) << 4;

    // L0 for slice s -> h0[buf] (this wave's 32-c half)
    auto do_L0 = [&](int s, int buf) {
        const int pxl = s * 32 + P;
        const int swz = (pxl & 15) << 4;
        short8 xf[5];
        #pragma unroll
        for (int ks = 0; ks < 5; ++ks)
            xf[ks] = *(const short8*)(xt + ((pxl * 256 + ks * 32 + H * 16) ^ swz));
        f32x16 acc = {};
        #pragma unroll
        for (int ks = 0; ks < 5; ++ks)
            acc = __builtin_amdgcn_mfma_f32_32x32x16_bf16(w0f[ks], xf[ks], acc, 0, 0, 0);
        char* hb = hb_iw + buf * 16384;
        #pragma unroll
        for (int q = 0; q < 4; ++q) {
            uint2_ pk2;
            pk2.x = pkbf2(fmaxf(acc[q * 4 + 0], 0.f), fmaxf(acc[q * 4 + 1], 0.f));
            pk2.y = pkbf2(fmaxf(acc[q * 4 + 2], 0.f), fmaxf(acc[q * 4 + 3], 0.f));
            *(uint2_*)(hb + ((P * 128 + kh * 64 + q * 16 + H * 8) ^ swh)) = pk2;
        }
    };

    __syncthreads();            // xt ready (fixes R7's prologue race)
    do_L0(0, 0);
    float vprev = 0.f;

    #pragma unroll
    for (int s = 0; s < 4; ++s) {
        const int buf = s & 1;
        __syncthreads();        // h0[buf] complete; vpart[buf^1] complete
        // store slice s-1 (pipelined one slice behind)
        if (s > 0 && kh == 0 && lane < 32)
            out[(size_t)m * HW + pxg0 + (s - 1) * 32 + lane] =
                vprev + vpart[(buf ^ 1) * 128 + iw * 32 + lane] + b2;
        // next slice's L0 -> h0[buf^1], concurrent with L1/L2(s)
        if (s < 3) do_L0(s + 1, buf ^ 1);
        // L1(s): full-c h0 (both k-halves) -> this wave's 32 k-outputs
        char* hb = hb_iw + buf * 16384;
        short8 hf[4];
        #pragma unroll
        for (int ks = 0; ks < 4; ++ks)
            hf[ks] = *(const short8*)(hb + ((P * 128 + ks * 32 + H * 16) ^ swh));
        f32x16 acc1 = bias1;
        #pragma unroll
        for (int ks = 0; ks < 4; ++ks)
            acc1 = __builtin_amdgcn_mfma_f32_32x32x16_bf16(w1f[ks], hf[ks], acc1, 0, 0, 0);
        // L2: 64->1 fp32 VALU over this lane's 16 c-rows, + partner half-wave
        float v = 0.f;
        #pragma unroll
        for (int e = 0; e < 16; ++e)
            v += w2v[e] * fmaxf(acc1[e], 0.f);
        v += __shfl_xor(v, 32);          // sum H=0/1 row groups (same px)
        if (kh == 1) { if (lane < 32) vpart[buf * 128 + iw * 32 + lane] = v; }
        else vprev = v;
    }
    __syncthreads();            // vpart[1] (slice 3) ready
    if (kh == 0 && lane < 32)
        out[(size_t)m * HW + pxg0 + 3 * 32 + lane] =
            vprev + vpart[128 + iw * 32 + lane] + b2;
}

extern "C" void kernel_launch(void* const* d_in, const int* in_sizes, int n_in,
                              void* d_out, int out_size, void* d_ws, size_t ws_size,
                              hipStream_t stream) {
    const float* x      = (const float*)d_in[0];
    const float* params = (const float*)d_in[1];
    float* out          = (float*)d_out;

    const int N = in_sizes[0] / (64 * HW);   // 4
    const int M = in_sizes[1] / NPARAM;      // 32
    const int num_ins = M / N;               // 8 (kernel assumes 8: 2 groups x 4)

    dim3 grid((HW + 127) / 128, N * 2);      // 125 x 8 = 1000 blocks
    condlane_mfma32<<<grid, 512, 66560, stream>>>(x, params, out, num_ins);
}

// Round 11
// 26.207 us; speedup vs baseline: 2.6834x; 1.1081x over previous
//
#include <hip/hip_runtime.h>

typedef __attribute__((ext_vector_type(8)))  short    short8;   // 8 bf16 (K=32 A/B frag)
typedef __attribute__((ext_vector_type(4)))  short    s16x4;    // 4 bf16 (K=16 A/B frag)
typedef __attribute__((ext_vector_type(4)))  float    f32x4;    // 16x16 C/D frag
typedef __attribute__((ext_vector_type(4)))  unsigned uint4_;
typedef __attribute__((ext_vector_type(2)))  unsigned uint2_;

#define HW     16000
#define WWID   200
#define NPARAM 8513
// raw param offsets: w0[64][66] @0, w1[64][64] @4224, w2 @8320, b0 @8384, b1 @8448, b2 @8512

__device__ __forceinline__ unsigned pkbf2(float a, float b) {   // 1 VALU op (RNE)
    unsigned r;
    asm("v_cvt_pk_bf16_f32 %0, %1, %2" : "=v"(r) : "v"(a), "v"(b));
    return r;
}
__device__ __forceinline__ short8 mk8(unsigned a, unsigned b, unsigned c, unsigned d) {
    uint4_ u; u.x = a; u.y = b; u.z = c; u.w = d;
    return __builtin_bit_cast(short8, u);
}
__device__ __forceinline__ s16x4 mk4(unsigned a, unsigned b) {
    uint2_ u; u.x = a; u.y = b;
    return __builtin_bit_cast(s16x4, u);
}
// K=16 bf16 MFMA via inline asm. The leading s_nop 2 covers the CDNA
// "VALU write -> MFMA read SrcA/B/C" manually-inserted-wait-state hazard that
// the compiler's hazard recognizer cannot see through inline asm (R10's 2.2
// absmax failure). A,B = 2-VGPR tuples (4 bf16), C/D = 4-VGPR tied.
__device__ __forceinline__ void mfma16(f32x4& acc, s16x4 a, s16x4 b) {
    asm("s_nop 2\n\tv_mfma_f32_16x16x16_bf16 %0, %1, %2, %0"
        : "+v"(acc) : "v"(a), "v"(b));
}

// block = 512 threads (8 waves); wave wid owns FULL instance m = n*num_ins+wid.
// relu(acc0[ks]) packed to bf16 IS L1's B operand for K-chunk ks (layout
// identity): h0 never touches LDS; slice loop has no barriers/shuffles/LDS-wr.
// LDS: xt [256 px][128 ch] bf16 XOR-swizzled (64KB) only. One barrier total.
__global__ __launch_bounds__(512, 2) void condlane_reg(
    const float* __restrict__ x,        // [N, 64, HW]
    const float* __restrict__ params,   // [M, 8513]
    float* __restrict__ out,            // [M, HW]
    int num_ins)
{
    extern __shared__ char lds_[];
    char* xt = lds_;                    // 65536 B
    const int tid  = threadIdx.x;
    const int lane = tid & 63;
    const int wid  = tid >> 6;
    const int n    = blockIdx.y;
    const int pxg0 = blockIdx.x * 256;
    const int g    = (lane >> 4) & 3;
    const int px16 = lane & 15;

    // ---- stage x tile: [256 px][128 ch] bf16, swizzle byte ^= (p&15)<<4 ----
    {
        const int p   = tid & 255;
        const int sel = tid >> 8;       // 0..1, 32 fp32 channels each
        const int pc  = min(pxg0 + p, HW - 1);
        const float* xp = x + (size_t)n * 64 * HW + pc;
        #pragma unroll
        for (int it = 0; it < 4; ++it) {
            int c0 = sel * 32 + it * 8;
            uint4_ d;
            d.x = pkbf2(xp[(size_t)(c0 + 0) * HW], xp[(size_t)(c0 + 1) * HW]);
            d.y = pkbf2(xp[(size_t)(c0 + 2) * HW], xp[(size_t)(c0 + 3) * HW]);
            d.z = pkbf2(xp[(size_t)(c0 + 4) * HW], xp[(size_t)(c0 + 5) * HW]);
            d.w = pkbf2(xp[(size_t)(c0 + 6) * HW], xp[(size_t)(c0 + 7) * HW]);
            *(uint4_*)(xt + ((p * 256 + c0 * 2) ^ ((p & 15) << 4))) = d;
        }
        // const K-channels 64..95 = {lx, ly, 1, 0 ...}
        const int pg = pxg0 + p;        // values for pg>=HW never consumed
        float lx = (float)(pg % WWID) * (1.0f / WWID);
        float ly = (float)(pg / WWID) * (1.0f / WWID);   // source bug: also /W
        uint4_ z;  z.x = 0; z.y = 0; z.z = 0; z.w = 0;
        uint4_ cv; cv.x = pkbf2(lx, ly); cv.y = pkbf2(1.f, 0.f); cv.z = 0; cv.w = 0;
        int ba = (p * 256 + 128 + sel * 32) ^ ((p & 15) << 4);
        int bb = (p * 256 + 144 + sel * 32) ^ ((p & 15) << 4);
        *(uint4_*)(xt + ba) = (sel == 0) ? cv : z;
        *(uint4_*)(xt + bb) = z;
    }

    // ---- per-wave full-instance weight gather into register fragments ----
    const int m = n * num_ins + wid;    // 8 waves == num_ins
    const float* pm = params + (size_t)m * NPARAM;

    short8 w0f[3][4];                   // L0: K=96 frags (x32 shape)
    s16x4  w1f4[4][4];                  // L1: [kb out-block][ks K-chunk] (x16 shape)
    #pragma unroll
    for (int kb = 0; kb < 4; ++kb) {
        const int k = kb * 16 + px16;   // A-frag row = lane&15
        #pragma unroll
        for (int ch = 0; ch < 2; ++ch) {
            const float* s0 = pm + k * 66 + 2 + ch * 32 + g * 8;  // w0 x-cols
            w0f[ch][kb] = mk8(pkbf2(s0[0], s0[1]), pkbf2(s0[2], s0[3]),
                              pkbf2(s0[4], s0[5]), pkbf2(s0[6], s0[7]));
        }
        // K-channels 64..95 = {lx, ly, 1, 0...} -> cols {w00, w01, b0, 0...}
        float a = (g == 0) ? pm[k * 66 + 0] : 0.f;
        float b = (g == 0) ? pm[k * 66 + 1] : 0.f;
        float c = (g == 0) ? pm[8384 + k]   : 0.f;
        w0f[2][kb] = mk8(pkbf2(a, b), pkbf2(c, 0.f), 0u, 0u);
        // w1 A-frag (x16 shape): row k2 = kb*16 + (lane&15), k = g*4 + j
        #pragma unroll
        for (int ks = 0; ks < 4; ++ks) {
            const float* s1 = pm + 4224 + (kb * 16 + px16) * 64 + ks * 16 + g * 4;
            w1f4[kb][ks] = mk4(pkbf2(s1[0], s1[1]), pkbf2(s1[2], s1[3]));
        }
    }
    f32x4 bias1[4], w2v[4];
    #pragma unroll
    for (int kb = 0; kb < 4; ++kb)
        #pragma unroll
        for (int r = 0; r < 4; ++r) {   // acc1[kb] reg r <-> k2 = kb*16 + g*4 + r
            bias1[kb][r] = pm[8448 + kb * 16 + g * 4 + r];
            w2v[kb][r]   = pm[8320 + kb * 16 + g * 4 + r];
        }
    const float b2 = pm[8512] - 2.19f;

    __syncthreads();                    // xt ready — the only barrier

    const int swz = px16 << 4;          // (pxl&15)<<4 == (lane&15)<<4 always
    const int nsl = min(16, (HW - pxg0) >> 4);

    for (int s = 0; s < 16; ++s) {
        const int pxl = s * 16 + px16;
        // x B-frags (K=96)
        short8 xf[3];
        #pragma unroll
        for (int ch = 0; ch < 3; ++ch)
            xf[ch] = *(const short8*)(xt + ((pxl * 256 + ch * 64 + g * 16) ^ swz));
        // layer 0: 12 MFMA (K=96), acc = 0 (loc+bias folded)
        f32x4 acc0[4];
        #pragma unroll
        for (int kb = 0; kb < 4; ++kb)
            #pragma unroll
            for (int j = 0; j < 4; ++j) acc0[kb][j] = 0.f;
        #pragma unroll
        for (int ch = 0; ch < 3; ++ch)
            #pragma unroll
            for (int kb = 0; kb < 4; ++kb)
                acc0[kb] = __builtin_amdgcn_mfma_f32_16x16x32_bf16(w0f[ch][kb], xf[ch], acc0[kb], 0, 0, 0);
        // relu -> bf16 IN REGISTERS: acc0[ks] becomes L1's B-frag for chunk ks
        s16x4 hf[4];
        #pragma unroll
        for (int ks = 0; ks < 4; ++ks)
            hf[ks] = mk4(pkbf2(fmaxf(acc0[ks][0], 0.f), fmaxf(acc0[ks][1], 0.f)),
                         pkbf2(fmaxf(acc0[ks][2], 0.f), fmaxf(acc0[ks][3], 0.f)));
        // layer 1: 16 x K=16 MFMA (inline asm, hazard-protected)
        f32x4 acc1[4];
        #pragma unroll
        for (int kb = 0; kb < 4; ++kb) acc1[kb] = bias1[kb];
        #pragma unroll
        for (int ks = 0; ks < 4; ++ks)
            #pragma unroll
            for (int kb = 0; kb < 4; ++kb)
                mfma16(acc1[kb], w1f4[kb][ks], hf[ks]);
        // exit hazard: MFMA write -> VALU read. Tie the nops to the accs so the
        // following reads are data-ordered AFTER the wait (R10 got this wrong).
        asm("s_nop 7\n\ts_nop 7"
            : "+v"(acc1[0]), "+v"(acc1[1]), "+v"(acc1[2]), "+v"(acc1[3]));
        // layer 2: 64->1 fp32 VALU + cross-group reduce
        float v = 0.f;
        #pragma unroll
        for (int kb = 0; kb < 4; ++kb)
            #pragma unroll
            for (int r = 0; r < 4; ++r)
                v += w2v[kb][r] * fmaxf(acc1[kb][r], 0.f);
        v += __shfl_xor(v, 16);
        v += __shfl_xor(v, 32);
        if (lane < 16 && s < nsl)
            out[(size_t)m * HW + pxg0 + s * 16 + lane] = v + b2;
    }
}

extern "C" void kernel_launch(void* const* d_in, const int* in_sizes, int n_in,
                              void* d_out, int out_size, void* d_ws, size_t ws_size,
                              hipStream_t stream) {
    const float* x      = (const float*)d_in[0];
    const float* params = (const float*)d_in[1];
    float* out          = (float*)d_out;

    const int N = in_sizes[0] / (64 * HW);   // 4
    const int M = in_sizes[1] / NPARAM;      // 32
    const int num_ins = M / N;               // 8

    dim3 grid((HW + 255) / 256, N);          // 63 x 4 = 252 blocks
    condlane_reg<<<grid, 512, 65536, stream>>>(x, params, out, num_ins);
}